// Round 6
// baseline (531.222 us; speedup 1.0000x reference)
//
#include <hip/hip_runtime.h>
#include <math.h>
#include <stdint.h>

// LinearAttention  N=4, S=8192, D_IN=1024, ATTN_DIM=1024, OUT_DIM=1024
// R10: algebraic restructure.  In the reference,
//   V = Q*KV/(Q*Ksum + 1e-6) = KV/(Ksum + 1e-6/Q),  Q = elu(.)+1 > 0,
// and 1e-6/Q <= ~4e-4 vs Ksum ~ 8.8e3  ->  V is Q-independent to ~5e-8
// relative.  out rows within a batch are identical:
//   out[m,:] = gelu(bo + (KV_n/Ks_n) @ wo),   n = m>>13.
// So: drop Q projection / Q store / vprime / the 68.7-GFLOP out GEMM.
// Pipeline: memset -> wtrans(wk,wv) -> xconv(full) -> kv_mfma (K,V proj +
// KV/Ks reductions only, single dispatch, BM=256 BN=128 BK=64, cross-tile
// register pipeline from R9) -> outk (fp32 GEMV y_n = gelu(bo+(KV/Ks)@wo),
// fused 128MB broadcast write).  9 dispatches -> 5.
// ws: xb 64MB | wkT,wvT 4MB | KV,Ks 32KB   (no halves needed anymore).

typedef __attribute__((ext_vector_type(8))) __bf16 bf16x8;
typedef __attribute__((ext_vector_type(8))) unsigned short ushort8;
typedef __attribute__((ext_vector_type(4))) float f32x4;

__device__ __forceinline__ unsigned short f2bf(float f) {
    unsigned int u = __builtin_bit_cast(unsigned int, f);
    unsigned int r = (u + 0x7fffu + ((u >> 16) & 1u)) >> 16;   // RNE
    return (unsigned short)r;
}
__device__ __forceinline__ float elu1(float v) { return v > 0.f ? v + 1.f : __expf(v); }
__device__ __forceinline__ float gelu_tanh(float v) {
    float u = 1.5957691216057308f * (v + 0.044715f * v * v * v);
    float e = __expf(u);
    float th = 1.f - 2.f / (e + 1.f);
    return 0.5f * v * (1.f + th);
}
__device__ __forceinline__ void glds16(const void* g, void* l) {
    __builtin_amdgcn_global_load_lds(
        (const __attribute__((address_space(1))) unsigned int*)(uintptr_t)g,
        (__attribute__((address_space(3))) unsigned int*)(uintptr_t)l, 16, 0, 0);
}

#define KBAR()  asm volatile("s_barrier" ::: "memory")
#define LGKM0() do { asm volatile("s_waitcnt lgkmcnt(0)" ::: "memory"); \
                     __builtin_amdgcn_sched_barrier(0); } while (0)
#define VM8()   asm volatile("s_waitcnt vmcnt(8)" ::: "memory")
#define VM0()   asm volatile("s_waitcnt vmcnt(0)" ::: "memory")

#define LDF(P, OFF) __builtin_bit_cast(bf16x8, *(const ushort8*)&(P)[OFF])

// ---------------------------------------------------------------------------
// x fp32 -> bf16, full tensor (32768 rows) in one launch
// ---------------------------------------------------------------------------
__global__ __launch_bounds__(256) void xconv(const float* __restrict__ x,
                                             unsigned short* __restrict__ xb)
{
    const size_t base = ((size_t)blockIdx.x * 256 + threadIdx.x) * 8;
    float4 a = *(const float4*)&x[base];
    float4 b = *(const float4*)&x[base + 4];
    ushort8 o;
    o[0] = f2bf(a.x); o[1] = f2bf(a.y); o[2] = f2bf(a.z); o[3] = f2bf(a.w);
    o[4] = f2bf(b.x); o[5] = f2bf(b.y); o[6] = f2bf(b.z); o[7] = f2bf(b.w);
    *(ushort8*)&xb[base] = o;
}

// ---------------------------------------------------------------------------
// weight transpose + convert: wk, wv only (blockIdx.z)
// ---------------------------------------------------------------------------
__global__ __launch_bounds__(256) void wtrans(const float* __restrict__ wk,
                                              const float* __restrict__ wv,
                                              unsigned short* __restrict__ wT)
{
    __shared__ float tile[64][65];
    const int z = blockIdx.z;
    const float* w = (z == 0) ? wk : wv;
    unsigned short* dst = wT + (size_t)z * 1048576;
    const int t  = threadIdx.x;
    const int n0 = blockIdx.x * 64;
    const int k0 = blockIdx.y * 64;
    const int r  = t >> 2;
    const int c4 = (t & 3) * 16;
    #pragma unroll
    for (int j = 0; j < 4; ++j) {
        float4 v = *(const float4*)&w[(size_t)(k0 + r) * 1024 + n0 + c4 + j * 4];
        tile[r][c4 + j * 4 + 0] = v.x; tile[r][c4 + j * 4 + 1] = v.y;
        tile[r][c4 + j * 4 + 2] = v.z; tile[r][c4 + j * 4 + 3] = v.w;
    }
    __syncthreads();
    const int nn = t >> 2;
    const int kc = (t & 3) * 16;
    ushort8 o0, o1;
    #pragma unroll
    for (int j = 0; j < 8; ++j) o0[j] = f2bf(tile[kc + j][nn]);
    #pragma unroll
    for (int j = 0; j < 8; ++j) o1[j] = f2bf(tile[kc + 8 + j][nn]);
    *(ushort8*)&dst[(size_t)(n0 + nn) * 1024 + k0 + kc]     = o0;
    *(ushort8*)&dst[(size_t)(n0 + nn) * 1024 + k0 + kc + 8] = o1;
}

// ---------------------------------------------------------------------------
// K,V projections + KV/Ks reductions.  BM=256, BN=128 (shared h for K and V),
// BK=64, 8 waves (4m x 2n), wave tile 64x64 per matrix (4mi x 4nj), 64 MFMA
// per wave per K-tile.  Cross-tile register pipeline (R9), single barrier per
// tile, A/B double-buffered, per-wave 8 staged ops/tile -> mid-tile vmcnt(0)
// on loads issued a full tile earlier.  LDS 144KB, 1 block/CU.
// No output matrix store: only KV/Ks atomics.
// ---------------------------------------------------------------------------
__global__ __launch_bounds__(512, 2) void kv_mfma(
    const unsigned short* __restrict__ xb,       // [32768,1024] bf16
    const unsigned short* __restrict__ wkT,
    const unsigned short* __restrict__ wvT,
    const float* __restrict__ bk, const float* __restrict__ bv,
    float* __restrict__ KV, float* __restrict__ Ks)
{
    __shared__ unsigned short Alds[2][256 * 64];     // 64 KB
    __shared__ unsigned short Blds[2][2][128 * 64];  // 64 KB [buf][mat]
    __shared__ float redkv[16][128];                 // 8 KB
    __shared__ float redks[16][128];                 // 8 KB

    const int t = threadIdx.x;
    // bijective XCD swizzle: 1024 blocks (8 h x 128 m), chunk 128 -> each XCD
    // owns 16 consecutive m-blocks x all 8 h-blocks (A-rows fetched once/L2).
    const unsigned int nlin = blockIdx.x + 8u * blockIdx.y;
    const unsigned int swz  = (nlin & 7u) * 128u + (nlin >> 3);
    const int h0   = (int)(swz & 7u) * 128;
    const int m0   = (int)(swz >> 3) * 256;
    const int bidx = m0 >> 13;

    const int lane = t & 63, wid = t >> 6;
    const int wm = wid >> 1, wn = wid & 1;
    const int lr = lane & 15, quad = lane >> 4;

    const int sA   = wid * 64 + lane;
    const int xks0 = ((quad)     ^ (lr & 7)) * 8;
    const int xks1 = ((quad | 4) ^ (lr & 7)) * 8;
    const int arow = (wm * 64 + lr) * 64;
    const int brow = (wn * 64 + lr) * 64;

    // A unit u = 64 rows; all 8 waves issue 1 glds each (4 units/tile).
    auto stA = [&](int kt, int u, int buf) {
        const int s = u * 512 + sA;
        const int r = s >> 3;
        const int j = (s & 7) ^ (r & 7);
        glds16(&xb[(size_t)(m0 + r) * 1024 + kt * 64 + j * 8],
               &Alds[buf][(u * 512 + wid * 64) * 8]);
    };
    // B: per matrix 128 rows = 2 units of 64.
    auto stB = [&](const unsigned short* w, int mat, int kt, int u, int buf) {
        const int r = sA >> 3;
        const int j = (sA & 7) ^ (r & 7);
        glds16(&w[(size_t)(h0 + u * 64 + r) * 1024 + kt * 64 + j * 8],
               &Blds[buf][mat][(u * 512 + wid * 64) * 8]);
    };

    f32x4 acck[4][4], accv[4][4];
    #pragma unroll
    for (int mi = 0; mi < 4; ++mi)
        #pragma unroll
        for (int nj = 0; nj < 4; ++nj) {
            acck[mi][nj] = (f32x4){0.f, 0.f, 0.f, 0.f};
            accv[mi][nj] = (f32x4){0.f, 0.f, 0.f, 0.f};
        }

    // prologue: stage tiles 0 and 1 (8 ops each/wave); drain tile 0
    #pragma unroll
    for (int u = 0; u < 4; ++u) stA(0, u, 0);
    stB(wkT, 0, 0, 0, 0); stB(wkT, 0, 0, 1, 0);
    stB(wvT, 1, 0, 0, 0); stB(wvT, 1, 0, 1, 0);
    #pragma unroll
    for (int u = 0; u < 4; ++u) stA(1, u, 1);
    stB(wkT, 0, 1, 0, 1); stB(wkT, 0, 1, 1, 1);
    stB(wvT, 1, 1, 0, 1); stB(wvT, 1, 1, 1, 1);
    VM8();                                   // drain tile0, keep tile1's 8
    KBAR();

    bf16x8 af0[4], af1[4], bk0[4], bk1[4], bv0[4], bv1[4];
    #pragma unroll
    for (int mi = 0; mi < 4; ++mi)
        af0[mi] = LDF(Alds[0], arow + mi * 1024 + xks0);
    #pragma unroll
    for (int nj = 0; nj < 4; ++nj) {
        bk0[nj] = LDF(Blds[0][0], brow + nj * 1024 + xks0);
        bv0[nj] = LDF(Blds[0][1], brow + nj * 1024 + xks0);
    }

    #pragma unroll
    for (int kt = 0; kt < 16; ++kt) {
        const int ab = kt & 1, nb = (kt + 1) & 1;
        // ---- read ks1[kt] -> set1 (drains under MFMA-ks0) ----
        #pragma unroll
        for (int mi = 0; mi < 4; ++mi)
            af1[mi] = LDF(Alds[ab], arow + mi * 1024 + xks1);
        #pragma unroll
        for (int nj = 0; nj < 4; ++nj) {
            bk1[nj] = LDF(Blds[ab][0], brow + nj * 1024 + xks1);
            bv1[nj] = LDF(Blds[ab][1], brow + nj * 1024 + xks1);
        }
        // ---- MFMA ks0 (fragments read last iter) ----
        __builtin_amdgcn_s_setprio(1);
        #pragma unroll
        for (int mi = 0; mi < 4; ++mi)
            #pragma unroll
            for (int nj = 0; nj < 4; ++nj) {
                acck[mi][nj] = __builtin_amdgcn_mfma_f32_16x16x32_bf16(af0[mi], bk0[nj], acck[mi][nj], 0, 0, 0);
                accv[mi][nj] = __builtin_amdgcn_mfma_f32_16x16x32_bf16(af0[mi], bv0[nj], accv[mi][nj], 0, 0, 0);
            }
        __builtin_amdgcn_s_setprio(0);

        if (kt < 15) {
            VM0();        // tile kt+1 staging (issued a full tile ago)
            LGKM0();      // tile-kt reads complete before overwrite
            KBAR();
            // ---- read ks0[kt+1] -> set0 (drains under MFMA-ks1) ----
            #pragma unroll
            for (int mi = 0; mi < 4; ++mi)
                af0[mi] = LDF(Alds[nb], arow + mi * 1024 + xks0);
            #pragma unroll
            for (int nj = 0; nj < 4; ++nj) {
                bk0[nj] = LDF(Blds[nb][0], brow + nj * 1024 + xks0);
                bv0[nj] = LDF(Blds[nb][1], brow + nj * 1024 + xks0);
            }
            // ---- stage tile kt+2 into buf ab (fully read, race-free) ----
            if (kt + 2 < 16) {
                stB(wkT, 0, kt + 2, 0, ab); stB(wkT, 0, kt + 2, 1, ab);
                stB(wvT, 1, kt + 2, 0, ab); stB(wvT, 1, kt + 2, 1, ab);
                stA(kt + 2, 0, ab); stA(kt + 2, 1, ab);
                stA(kt + 2, 2, ab); stA(kt + 2, 3, ab);
            }
        }
        // ---- MFMA ks1 ----
        __builtin_amdgcn_s_setprio(1);
        #pragma unroll
        for (int mi = 0; mi < 4; ++mi)
            #pragma unroll
            for (int nj = 0; nj < 4; ++nj) {
                acck[mi][nj] = __builtin_amdgcn_mfma_f32_16x16x32_bf16(af1[mi], bk1[nj], acck[mi][nj], 0, 0, 0);
                accv[mi][nj] = __builtin_amdgcn_mfma_f32_16x16x32_bf16(af1[mi], bv1[nj], accv[mi][nj], 0, 0, 0);
            }
        __builtin_amdgcn_s_setprio(0);
    }

    // ---- epilogue: bias, elu+1 on K, KV/Ksum partials, block reduce ----
    float bkv_[4], bvv_[4];
    #pragma unroll
    for (int nj = 0; nj < 4; ++nj) {
        const int h = h0 + wn * 64 + nj * 16 + lr;
        bkv_[nj] = bk[h]; bvv_[nj] = bv[h];
    }
    float kvp[4] = {0.f, 0.f, 0.f, 0.f}, ksp[4] = {0.f, 0.f, 0.f, 0.f};
    #pragma unroll
    for (int mi = 0; mi < 4; ++mi)
        #pragma unroll
        for (int nj = 0; nj < 4; ++nj)
            #pragma unroll
            for (int r = 0; r < 4; ++r) {
                float kk = elu1(acck[mi][nj][r] + bkv_[nj]);
                float vv = accv[mi][nj][r] + bvv_[nj];
                kvp[nj] = fmaf(kk, vv, kvp[nj]);
                ksp[nj] += kk;
            }
    #pragma unroll
    for (int nj = 0; nj < 4; ++nj) {
        redkv[wm * 4 + quad][wn * 64 + nj * 16 + lr] = kvp[nj];
        redks[wm * 4 + quad][wn * 64 + nj * 16 + lr] = ksp[nj];
    }
    __syncthreads();
    if (t < 128) {
        float s = 0.f;
        #pragma unroll
        for (int g = 0; g < 16; ++g) s += redkv[g][t];
        atomicAdd(&KV[bidx * 1024 + h0 + t], s);
    } else if (t < 256) {
        const int c = t - 128;
        float s = 0.f;
        #pragma unroll
        for (int g = 0; g < 16; ++g) s += redks[g][c];
        atomicAdd(&Ks[bidx * 1024 + h0 + c], s);
    }
}

// ---------------------------------------------------------------------------
// out: y_n = gelu(bo + (KV_n/Ks_n) @ wo), broadcast to all 8192 rows of
// batch n.  Grid (16 j-chunks x 8 m-chunks x 4 n); per block: fp32 GEMV for
// 64 outputs (4-way h-split) then 1024 rows x 64 cols of float4 stores.
// ---------------------------------------------------------------------------
__global__ __launch_bounds__(256) void outk(
    const float* __restrict__ wo, const float* __restrict__ bo,
    const float* __restrict__ KV, const float* __restrict__ Ks,
    float* __restrict__ out)
{
    __shared__ float kvr[1024];
    __shared__ float part[4][64];
    __shared__ float yld[64];

    const int t  = threadIdx.x;
    const int j0 = blockIdx.x * 64;
    const int mc = blockIdx.y;           // 0..7  (1024-row chunk)
    const int n  = blockIdx.z;           // 0..3

    {   // kvr = KV/Ks (the Q-cancelled V' row, exact to ~5e-8 rel)
        float4 kv4 = *(const float4*)&KV[n * 1024 + t * 4];
        float4 ks4 = *(const float4*)&Ks[n * 1024 + t * 4];
        kvr[t * 4 + 0] = kv4.x / ks4.x;
        kvr[t * 4 + 1] = kv4.y / ks4.y;
        kvr[t * 4 + 2] = kv4.z / ks4.z;
        kvr[t * 4 + 3] = kv4.w / ks4.w;
    }
    __syncthreads();

    const int jj = j0 + (t & 63);
    const int hq = t >> 6;
    float acc = 0.f;
    #pragma unroll 4
    for (int h = hq * 256; h < hq * 256 + 256; ++h)
        acc = fmaf(kvr[h], wo[(size_t)h * 1024 + jj], acc);
    part[hq][t & 63] = acc;
    __syncthreads();
    if (t < 64) {
        float s = part[0][t] + part[1][t] + part[2][t] + part[3][t];
        yld[t] = gelu_tanh(s + bo[j0 + t]);
    }
    __syncthreads();

    const int fc = t & 15;               // float4 col within the 64-col stripe
    const int rg = t >> 4;               // 0..15 row group
    const float4 v = *(const float4*)&yld[fc * 4];
    const size_t mbase = (size_t)n * 8192 + (size_t)mc * 1024;
    #pragma unroll 4
    for (int it = 0; it < 64; ++it) {
        const size_t m = mbase + rg + (size_t)it * 16;
        *(float4*)&out[m * 1024 + j0 + fc * 4] = v;
    }
}

extern "C" void kernel_launch(void* const* d_in, const int* in_sizes, int n_in,
                              void* d_out, int out_size, void* d_ws, size_t ws_size,
                              hipStream_t stream)
{
    const float* x  = (const float*)d_in[0];
    // d_in[1]=wq, d_in[2]=bq unused: the Q factor cancels (see header).
    const float* wk = (const float*)d_in[3];
    const float* bk = (const float*)d_in[4];
    const float* wv = (const float*)d_in[5];
    const float* bv = (const float*)d_in[6];
    const float* wo = (const float*)d_in[7];
    const float* bo = (const float*)d_in[8];
    float* out = (float*)d_out;

    // ws layout (bytes):
    //   [0, 64M)         xb bf16 (32768 x 1024)
    //   [64M, 68M)       wkT, wvT bf16 (2MB each)
    //   [68M, ...)       KV fp32 [4,1024], Ks fp32 [4,1024] (contiguous)
    char* wsb = (char*)d_ws;
    unsigned short* xb  = (unsigned short*)wsb;
    unsigned short* wkT = (unsigned short*)(wsb + 67108864ULL);
    unsigned short* wvT = wkT + 1048576;
    float* KV = (float*)(wsb + 67108864ULL + 2ULL * 2097152);
    float* Ks = KV + 4 * 1024;

    hipMemsetAsync(KV, 0, 2 * 4 * 1024 * sizeof(float), stream);

    wtrans<<<dim3(16, 16, 2), 256, 0, stream>>>(wk, wv, wkT);
    xconv<<<16384, 256, 0, stream>>>(x, xb);
    kv_mfma<<<dim3(8, 128), 512, 0, stream>>>(xb, wkT, wvT, bk, bv, KV, Ks);
    outk<<<dim3(16, 8, 4), 256, 0, stream>>>(wo, bo, KV, Ks, out);
}